// Round 1
// baseline (3522.913 us; speedup 1.0000x reference)
//
#include <hip/hip_runtime.h>
#include <math.h>

// ParityPonderGRU — fp32 correctness baseline.
// B=2048, E=512, H=1024, 20 ponder steps.
// ws layout (floats): gx[B*3H] | hA[B*H] | hB[B*H] | states[4*B]  (~42 MB)

#define B_N 2048
#define E_N 512
#define H_N 1024
#define G3 3072          // 3*H
#define NSTEPS 20

__device__ __forceinline__ float sigmoidf_(float x) { return 1.0f / (1.0f + expf(-x)); }

// ---------------- GEMM: gx = x @ W_ih^T + b_ih  (NT, both row-major K-inner) ----
__global__ __launch_bounds__(256)
void gemm_gx_kernel(const float* __restrict__ x,      // [B, E]
                    const float* __restrict__ W_ih,   // [3H, E]
                    const float* __restrict__ b_ih,   // [3H]
                    float* __restrict__ gx)           // [B, 3H]
{
    __shared__ float As[16][68];   // pad 68: row stride 272B = 17*16B (b128-aligned)
    __shared__ float Bs[16][68];
    const int tid = threadIdx.x;
    const int tx = tid & 15, ty = tid >> 4;
    const int row0 = blockIdx.y * 64;   // over B
    const int col0 = blockIdx.x * 64;   // over 3H
    const int lr = tid >> 2;            // 0..63
    const int lk = (tid & 3) << 2;      // 0,4,8,12
    float acc[4][4] = {};
    for (int k0 = 0; k0 < E_N; k0 += 16) {
        float4 av = *(const float4*)(x    + (size_t)(row0 + lr) * E_N + k0 + lk);
        float4 bv = *(const float4*)(W_ih + (size_t)(col0 + lr) * E_N + k0 + lk);
        As[lk+0][lr] = av.x; As[lk+1][lr] = av.y; As[lk+2][lr] = av.z; As[lk+3][lr] = av.w;
        Bs[lk+0][lr] = bv.x; Bs[lk+1][lr] = bv.y; Bs[lk+2][lr] = bv.z; Bs[lk+3][lr] = bv.w;
        __syncthreads();
        #pragma unroll
        for (int k = 0; k < 16; ++k) {
            float4 a4 = *(const float4*)&As[k][ty << 2];
            float4 b4 = *(const float4*)&Bs[k][tx << 2];
            float aa[4] = {a4.x, a4.y, a4.z, a4.w};
            float bb[4] = {b4.x, b4.y, b4.z, b4.w};
            #pragma unroll
            for (int i = 0; i < 4; ++i)
                #pragma unroll
                for (int j = 0; j < 4; ++j)
                    acc[i][j] = fmaf(aa[i], bb[j], acc[i][j]);
        }
        __syncthreads();
    }
    #pragma unroll
    for (int i = 0; i < 4; ++i) {
        const int r = row0 + (ty << 2) + i;
        #pragma unroll
        for (int j = 0; j < 4; ++j) {
            const int c = col0 + (tx << 2) + j;
            gx[(size_t)r * G3 + c] = acc[i][j] + b_ih[c];
        }
    }
}

// ---------------- Fused step GEMM: gh = h @ W_hh^T (+b_hh), gate epilogue -> h_out
// Each block computes a 64x64 tile of h_out, i.e. the SAME (row,col) tile of all
// three gate GEMMs (cols c, c+H, c+2H of W_hh) so gh never hits global memory.
__global__ __launch_bounds__(256)
void gemm_step_kernel(const float* __restrict__ h_in,  // [B, H]
                      const float* __restrict__ W_hh,  // [3H, H]
                      const float* __restrict__ b_hh,  // [3H]
                      const float* __restrict__ gx,    // [B, 3H]
                      float* __restrict__ h_out)       // [B, H]
{
    __shared__ float As[16][68];
    __shared__ float Bs[3][16][68];
    const int tid = threadIdx.x;
    const int tx = tid & 15, ty = tid >> 4;
    const int row0 = blockIdx.y * 64;   // over B  (32 blocks)
    const int col0 = blockIdx.x * 64;   // over H  (16 blocks)
    const int lr = tid >> 2;
    const int lk = (tid & 3) << 2;
    float accr[4][4] = {}, accz[4][4] = {}, accn[4][4] = {};
    for (int k0 = 0; k0 < H_N; k0 += 16) {
        float4 av = *(const float4*)(h_in + (size_t)(row0 + lr) * H_N + k0 + lk);
        As[lk+0][lr] = av.x; As[lk+1][lr] = av.y; As[lk+2][lr] = av.z; As[lk+3][lr] = av.w;
        #pragma unroll
        for (int g = 0; g < 3; ++g) {
            float4 bv = *(const float4*)(W_hh + (size_t)(g * H_N + col0 + lr) * H_N + k0 + lk);
            Bs[g][lk+0][lr] = bv.x; Bs[g][lk+1][lr] = bv.y; Bs[g][lk+2][lr] = bv.z; Bs[g][lk+3][lr] = bv.w;
        }
        __syncthreads();
        #pragma unroll
        for (int k = 0; k < 16; ++k) {
            float4 a4 = *(const float4*)&As[k][ty << 2];
            float4 r4 = *(const float4*)&Bs[0][k][tx << 2];
            float4 z4 = *(const float4*)&Bs[1][k][tx << 2];
            float4 n4 = *(const float4*)&Bs[2][k][tx << 2];
            float aa[4] = {a4.x, a4.y, a4.z, a4.w};
            float br[4] = {r4.x, r4.y, r4.z, r4.w};
            float bz[4] = {z4.x, z4.y, z4.z, z4.w};
            float bn[4] = {n4.x, n4.y, n4.z, n4.w};
            #pragma unroll
            for (int i = 0; i < 4; ++i)
                #pragma unroll
                for (int j = 0; j < 4; ++j) {
                    accr[i][j] = fmaf(aa[i], br[j], accr[i][j]);
                    accz[i][j] = fmaf(aa[i], bz[j], accz[i][j]);
                    accn[i][j] = fmaf(aa[i], bn[j], accn[i][j]);
                }
        }
        __syncthreads();
    }
    // Gate epilogue
    #pragma unroll
    for (int i = 0; i < 4; ++i) {
        const int r = row0 + (ty << 2) + i;
        #pragma unroll
        for (int j = 0; j < 4; ++j) {
            const int c = col0 + (tx << 2) + j;
            const float ghr = accr[i][j] + b_hh[c];
            const float ghz = accz[i][j] + b_hh[H_N + c];
            const float ghn = accn[i][j] + b_hh[2 * H_N + c];
            const float gxr = gx[(size_t)r * G3 + c];
            const float gxz = gx[(size_t)r * G3 + H_N + c];
            const float gxn = gx[(size_t)r * G3 + 2 * H_N + c];
            const float rr = sigmoidf_(gxr + ghr);
            const float zz = sigmoidf_(gxz + ghz);
            const float nn = tanhf(gxn + rr * ghn);
            h_out[(size_t)r * H_N + c] = (1.0f - zz) * nn + zz * h_in[(size_t)r * H_N + c];
        }
    }
}

// ---------------- h0 = gru_cell(x, 0): gh = b_hh; also init per-row states ----
__global__ __launch_bounds__(256)
void init_h0_kernel(const float* __restrict__ gx, const float* __restrict__ b_hh,
                    float* __restrict__ h0, float* __restrict__ states)
{
    const int idx = blockIdx.x * 256 + threadIdx.x;   // 0 .. B*H-1
    const int r = idx >> 10;          // /H
    const int c = idx & (H_N - 1);    // %H
    const float rr = sigmoidf_(gx[(size_t)r * G3 + c] + b_hh[c]);
    const float zz = sigmoidf_(gx[(size_t)r * G3 + H_N + c] + b_hh[H_N + c]);
    const float nn = tanhf(gx[(size_t)r * G3 + 2 * H_N + c] + rr * b_hh[2 * H_N + c]);
    h0[idx] = (1.0f - zz) * nn;       // + z*0
    if (idx < B_N) {
        states[idx]           = 1.0f;  // un_halted
        states[B_N + idx]     = 0.0f;  // halted
        states[2 * B_N + idx] = 0.0f;  // p_m
        states[3 * B_N + idx] = 0.0f;  // y_m
    }
}

// ---------------- Per-step halting: lam, y_n, state update, outputs ------------
__global__ __launch_bounds__(256)
void halt_kernel(const int n,
                 const float* __restrict__ h,      // [B, H]
                 const float* __restrict__ w_out, const float* __restrict__ b_out,
                 const float* __restrict__ w_lam, const float* __restrict__ b_lam,
                 const float* __restrict__ u,      // [NSTEPS, B]
                 float* __restrict__ states,
                 float* __restrict__ out_p, float* __restrict__ out_y,
                 float* __restrict__ out_pm, float* __restrict__ out_ym)
{
    const int row = blockIdx.x;
    const int tid = threadIdx.x;
    const float* hr = h + (size_t)row * H_N;
    const float4 hv = *(const float4*)&hr[tid << 2];
    const float4 wl = *(const float4*)&w_lam[tid << 2];
    const float4 wo = *(const float4*)&w_out[tid << 2];
    float s_lam = hv.x * wl.x + hv.y * wl.y + hv.z * wl.z + hv.w * wl.w;
    float s_out = hv.x * wo.x + hv.y * wo.y + hv.z * wo.z + hv.w * wo.w;
    #pragma unroll
    for (int off = 32; off > 0; off >>= 1) {
        s_lam += __shfl_down(s_lam, off);
        s_out += __shfl_down(s_out, off);
    }
    __shared__ float redl[4], redo[4];
    const int wid = tid >> 6;
    if ((tid & 63) == 0) { redl[wid] = s_lam; redo[wid] = s_out; }
    __syncthreads();
    if (tid == 0) {
        const float dlam = redl[0] + redl[1] + redl[2] + redl[3];
        const float dout = redo[0] + redo[1] + redo[2] + redo[3];
        const float lam = (n == NSTEPS) ? 1.0f : sigmoidf_(dlam + b_lam[0]);
        const float y_n = dout + b_out[0];
        float un = states[row];
        float ha = states[B_N + row];
        float pm = states[2 * B_N + row];
        float ym = states[3 * B_N + row];
        const float p_n = un * lam;
        un = un * (1.0f - lam);
        const float halt = (u[(size_t)(n - 1) * B_N + row] < lam ? 1.0f : 0.0f) * (1.0f - ha);
        pm = pm * (1.0f - halt) + p_n * halt;
        ym = ym * (1.0f - halt) + y_n * halt;
        ha += halt;
        states[row] = un;
        states[B_N + row] = ha;
        states[2 * B_N + row] = pm;
        states[3 * B_N + row] = ym;
        out_p[(size_t)(n - 1) * B_N + row] = p_n;
        out_y[(size_t)(n - 1) * B_N + row] = y_n;
        if (n == NSTEPS) { out_pm[row] = pm; out_ym[row] = ym; }
    }
}

extern "C" void kernel_launch(void* const* d_in, const int* in_sizes, int n_in,
                              void* d_out, int out_size, void* d_ws, size_t ws_size,
                              hipStream_t stream) {
    const float* x     = (const float*)d_in[0];
    const float* W_ih  = (const float*)d_in[1];
    const float* W_hh  = (const float*)d_in[2];
    const float* b_ih  = (const float*)d_in[3];
    const float* b_hh  = (const float*)d_in[4];
    const float* w_out = (const float*)d_in[5];
    const float* b_out = (const float*)d_in[6];
    const float* w_lam = (const float*)d_in[7];
    const float* b_lam = (const float*)d_in[8];
    const float* u     = (const float*)d_in[9];

    float* out_p  = (float*)d_out;                 // [20*2048]
    float* out_y  = out_p + (size_t)NSTEPS * B_N;  // [20*2048]
    float* out_pm = out_y + (size_t)NSTEPS * B_N;  // [2048]
    float* out_ym = out_pm + B_N;                  // [2048]

    float* ws    = (float*)d_ws;
    float* gx    = ws;                                   // B*3H
    float* hA    = gx + (size_t)B_N * G3;                // B*H
    float* hB    = hA + (size_t)B_N * H_N;               // B*H
    float* states = hB + (size_t)B_N * H_N;              // 4*B

    const dim3 blk(256);
    gemm_gx_kernel<<<dim3(G3 / 64, B_N / 64), blk, 0, stream>>>(x, W_ih, b_ih, gx);
    init_h0_kernel<<<dim3(B_N * H_N / 256), blk, 0, stream>>>(gx, b_hh, hA, states);

    float* hc = hA;
    float* hn = hB;
    for (int n = 1; n <= NSTEPS; ++n) {
        halt_kernel<<<dim3(B_N), blk, 0, stream>>>(n, hc, w_out, b_out, w_lam, b_lam, u,
                                                   states, out_p, out_y, out_pm, out_ym);
        if (n < NSTEPS) {
            gemm_step_kernel<<<dim3(H_N / 64, B_N / 64), blk, 0, stream>>>(hc, W_hh, b_hh, gx, hn);
            float* t = hc; hc = hn; hn = t;
        }
    }
}

// Round 2
// 1957.641 us; speedup vs baseline: 1.7996x; 1.7996x over previous
//
#include <hip/hip_runtime.h>
#include <math.h>

// ParityPonderGRU — MFMA split-fp16 (3-product) recurrent GEMM.
// B=2048, E=512, H=1024, 20 ponder steps.
// ws layout (floats): gx[B*3H] | hA[B*H] | hB[B*H] | states[4*B]  (~42 MB, same as r0)

#define B_N 2048
#define E_N 512
#define H_N 1024
#define G3  3072
#define NSTEPS 20
#define BK 32
#define NT (H_N / BK)   // 32 K-steps

typedef __attribute__((ext_vector_type(8))) _Float16 f16x8;
typedef __attribute__((ext_vector_type(4))) float    f32x4;

__device__ __forceinline__ float sigmoidf_(float x) { return 1.0f / (1.0f + expf(-x)); }

// fp32[8] -> fp16 hi + fp16 lo (Markidis split)
__device__ __forceinline__ void split8(const float4& v0, const float4& v1,
                                       f16x8& hi, f16x8& lo) {
  float s[8] = {v0.x, v0.y, v0.z, v0.w, v1.x, v1.y, v1.z, v1.w};
  #pragma unroll
  for (int e = 0; e < 8; ++e) {
    _Float16 h = (_Float16)s[e];
    hi[e] = h;
    lo[e] = (_Float16)(s[e] - (float)h);
  }
}

// ---------------- Fused step GEMM (MFMA): gh = h @ W_hh^T, gate epilogue -> h_out
// Block tile: 128 rows (B) x 64 cols (H) x 3 gates. 4 waves in 2x2 grid,
// wave tile 64x32 per gate. Split-fp16: acc += Ahi*Bhi + Ahi*Blo + Alo*Bhi.
__global__ __launch_bounds__(256, 1)
void gemm_step_mfma(const float* __restrict__ h_in,   // [B, H] fp32
                    const float* __restrict__ W_hh,   // [3H, H] fp32
                    const float* __restrict__ b_hh,   // [3H]
                    const float* __restrict__ gx,     // [B, 3H]
                    float* __restrict__ h_out)        // [B, H] fp32
{
  // pad 32 -> 40 halves: row stride 80 B = 5 x 16 B -> b128 ops hit all 8
  // bank-groups evenly (conflict-free for both ds_write and frag ds_read).
  __shared__ _Float16 Ah[2][128][40];
  __shared__ _Float16 Al[2][128][40];
  __shared__ _Float16 Bh[2][3][64][40];
  __shared__ _Float16 Bl[2][3][64][40];   // total 102.4 KB

  const int tid  = threadIdx.x;
  const int lane = tid & 63;
  const int wv   = tid >> 6;
  const int wr   = wv >> 1;    // 0..1 (row half)
  const int wc   = wv & 1;     // 0..1 (col half)
  const int row0 = blockIdx.y * 128;   // over B
  const int col0 = blockIdx.x * 64;    // over H

  // staging coords: thread -> (row, 8-wide k segment)
  const int srow = tid >> 2;          // 0..63
  const int skg  = (tid & 3) * 8;     // 0,8,16,24

  const float* aB0 = h_in + (size_t)(row0 + srow) * H_N + skg;
  const float* aB1 = aB0 + (size_t)64 * H_N;
  const float* bB0 = W_hh + (size_t)(0 * H_N + col0 + srow) * H_N + skg;
  const float* bB1 = W_hh + (size_t)(1 * H_N + col0 + srow) * H_N + skg;
  const float* bB2 = W_hh + (size_t)(2 * H_N + col0 + srow) * H_N + skg;

  float4 rA0a, rA0b, rA1a, rA1b;
  float4 rB0a, rB0b, rB1a, rB1b, rB2a, rB2b;

  auto load_regs = [&](int k0) {
    rA0a = *(const float4*)(aB0 + k0);  rA0b = *(const float4*)(aB0 + k0 + 4);
    rA1a = *(const float4*)(aB1 + k0);  rA1b = *(const float4*)(aB1 + k0 + 4);
    rB0a = *(const float4*)(bB0 + k0);  rB0b = *(const float4*)(bB0 + k0 + 4);
    rB1a = *(const float4*)(bB1 + k0);  rB1b = *(const float4*)(bB1 + k0 + 4);
    rB2a = *(const float4*)(bB2 + k0);  rB2b = *(const float4*)(bB2 + k0 + 4);
  };

  auto write_lds = [&](int p) {
    f16x8 hi, lo;
    split8(rA0a, rA0b, hi, lo);
    *(f16x8*)&Ah[p][srow][skg] = hi;        *(f16x8*)&Al[p][srow][skg] = lo;
    split8(rA1a, rA1b, hi, lo);
    *(f16x8*)&Ah[p][srow + 64][skg] = hi;   *(f16x8*)&Al[p][srow + 64][skg] = lo;
    split8(rB0a, rB0b, hi, lo);
    *(f16x8*)&Bh[p][0][srow][skg] = hi;     *(f16x8*)&Bl[p][0][srow][skg] = lo;
    split8(rB1a, rB1b, hi, lo);
    *(f16x8*)&Bh[p][1][srow][skg] = hi;     *(f16x8*)&Bl[p][1][srow][skg] = lo;
    split8(rB2a, rB2b, hi, lo);
    *(f16x8*)&Bh[p][2][srow][skg] = hi;     *(f16x8*)&Bl[p][2][srow][skg] = lo;
  };

  const f32x4 zero4 = {0.f, 0.f, 0.f, 0.f};
  f32x4 acc[3][4][2];
  #pragma unroll
  for (int g = 0; g < 3; ++g)
    #pragma unroll
    for (int mi = 0; mi < 4; ++mi)
      #pragma unroll
      for (int ni = 0; ni < 2; ++ni) acc[g][mi][ni] = zero4;

  const int lrow = lane & 15;
  const int lk   = (lane >> 4) * 8;

  auto compute = [&](int p) {
    f16x8 ah[4], al[4];
    #pragma unroll
    for (int mi = 0; mi < 4; ++mi) {
      ah[mi] = *(const f16x8*)&Ah[p][wr * 64 + mi * 16 + lrow][lk];
      al[mi] = *(const f16x8*)&Al[p][wr * 64 + mi * 16 + lrow][lk];
    }
    f16x8 bh[3][2], bl[3][2];
    #pragma unroll
    for (int g = 0; g < 3; ++g)
      #pragma unroll
      for (int ni = 0; ni < 2; ++ni) {
        bh[g][ni] = *(const f16x8*)&Bh[p][g][wc * 32 + ni * 16 + lrow][lk];
        bl[g][ni] = *(const f16x8*)&Bl[p][g][wc * 32 + ni * 16 + lrow][lk];
      }
    #pragma unroll
    for (int g = 0; g < 3; ++g)
      #pragma unroll
      for (int mi = 0; mi < 4; ++mi)
        #pragma unroll
        for (int ni = 0; ni < 2; ++ni) {
          f32x4 c = acc[g][mi][ni];
          c = __builtin_amdgcn_mfma_f32_16x16x32_f16(ah[mi], bh[g][ni], c, 0, 0, 0);
          c = __builtin_amdgcn_mfma_f32_16x16x32_f16(ah[mi], bl[g][ni], c, 0, 0, 0);
          c = __builtin_amdgcn_mfma_f32_16x16x32_f16(al[mi], bh[g][ni], c, 0, 0, 0);
          acc[g][mi][ni] = c;
        }
  };

  load_regs(0);
  write_lds(0);
  __syncthreads();
  for (int t = 0; t < NT; ++t) {
    const int p = t & 1;
    if (t + 1 < NT) load_regs((t + 1) * BK);   // issue early (T14)
    compute(p);
    if (t + 1 < NT) write_lds(p ^ 1);          // write late, other buffer
    __syncthreads();                           // one barrier per K-step
  }

  // Gate epilogue: D frag mapping col=lane&15, row=(lane>>4)*4+r  [m89]
  #pragma unroll
  for (int mi = 0; mi < 4; ++mi) {
    #pragma unroll
    for (int ni = 0; ni < 2; ++ni) {
      const int n = col0 + wc * 32 + ni * 16 + lrow;
      const float bhr = b_hh[n];
      const float bhz = b_hh[H_N + n];
      const float bhn = b_hh[2 * H_N + n];
      #pragma unroll
      for (int r = 0; r < 4; ++r) {
        const int m = row0 + wr * 64 + mi * 16 + (lane >> 4) * 4 + r;
        const float gr = acc[0][mi][ni][r] + bhr;
        const float gz = acc[1][mi][ni][r] + bhz;
        const float gn = acc[2][mi][ni][r] + bhn;
        const size_t gxb = (size_t)m * G3;
        const float rr = sigmoidf_(gx[gxb + n] + gr);
        const float zz = sigmoidf_(gx[gxb + H_N + n] + gz);
        const float nn = tanhf(gx[gxb + 2 * H_N + n] + rr * gn);
        const float hold = h_in[(size_t)m * H_N + n];
        h_out[(size_t)m * H_N + n] = (1.f - zz) * nn + zz * hold;
      }
    }
  }
}

// ---------------- GEMM: gx = x @ W_ih^T + b_ih  (fp32, one-time) ----------
__global__ __launch_bounds__(256)
void gemm_gx_kernel(const float* __restrict__ x,      // [B, E]
                    const float* __restrict__ W_ih,   // [3H, E]
                    const float* __restrict__ b_ih,   // [3H]
                    float* __restrict__ gx)           // [B, 3H]
{
    __shared__ float As[16][68];
    __shared__ float Bs[16][68];
    const int tid = threadIdx.x;
    const int tx = tid & 15, ty = tid >> 4;
    const int row0 = blockIdx.y * 64;
    const int col0 = blockIdx.x * 64;
    const int lr = tid >> 2;
    const int lk = (tid & 3) << 2;
    float acc[4][4] = {};
    for (int k0 = 0; k0 < E_N; k0 += 16) {
        float4 av = *(const float4*)(x    + (size_t)(row0 + lr) * E_N + k0 + lk);
        float4 bv = *(const float4*)(W_ih + (size_t)(col0 + lr) * E_N + k0 + lk);
        As[lk+0][lr] = av.x; As[lk+1][lr] = av.y; As[lk+2][lr] = av.z; As[lk+3][lr] = av.w;
        Bs[lk+0][lr] = bv.x; Bs[lk+1][lr] = bv.y; Bs[lk+2][lr] = bv.z; Bs[lk+3][lr] = bv.w;
        __syncthreads();
        #pragma unroll
        for (int k = 0; k < 16; ++k) {
            float4 a4 = *(const float4*)&As[k][ty << 2];
            float4 b4 = *(const float4*)&Bs[k][tx << 2];
            float aa[4] = {a4.x, a4.y, a4.z, a4.w};
            float bb[4] = {b4.x, b4.y, b4.z, b4.w};
            #pragma unroll
            for (int i = 0; i < 4; ++i)
                #pragma unroll
                for (int j = 0; j < 4; ++j)
                    acc[i][j] = fmaf(aa[i], bb[j], acc[i][j]);
        }
        __syncthreads();
    }
    #pragma unroll
    for (int i = 0; i < 4; ++i) {
        const int r = row0 + (ty << 2) + i;
        #pragma unroll
        for (int j = 0; j < 4; ++j) {
            const int c = col0 + (tx << 2) + j;
            gx[(size_t)r * G3 + c] = acc[i][j] + b_ih[c];
        }
    }
}

// ---------------- h0 = gru_cell(x, 0): gh = b_hh; init states --------------
__global__ __launch_bounds__(256)
void init_h0_kernel(const float* __restrict__ gx, const float* __restrict__ b_hh,
                    float* __restrict__ h0, float* __restrict__ states)
{
    const int idx = blockIdx.x * 256 + threadIdx.x;
    const int r = idx >> 10;
    const int c = idx & (H_N - 1);
    const float rr = sigmoidf_(gx[(size_t)r * G3 + c] + b_hh[c]);
    const float zz = sigmoidf_(gx[(size_t)r * G3 + H_N + c] + b_hh[H_N + c]);
    const float nn = tanhf(gx[(size_t)r * G3 + 2 * H_N + c] + rr * b_hh[2 * H_N + c]);
    h0[idx] = (1.0f - zz) * nn;
    if (idx < B_N) {
        states[idx]           = 1.0f;
        states[B_N + idx]     = 0.0f;
        states[2 * B_N + idx] = 0.0f;
        states[3 * B_N + idx] = 0.0f;
    }
}

// ---------------- Per-step halting -----------------------------------------
__global__ __launch_bounds__(256)
void halt_kernel(const int n,
                 const float* __restrict__ h,
                 const float* __restrict__ w_out, const float* __restrict__ b_out,
                 const float* __restrict__ w_lam, const float* __restrict__ b_lam,
                 const float* __restrict__ u,
                 float* __restrict__ states,
                 float* __restrict__ out_p, float* __restrict__ out_y,
                 float* __restrict__ out_pm, float* __restrict__ out_ym)
{
    const int row = blockIdx.x;
    const int tid = threadIdx.x;
    const float* hr = h + (size_t)row * H_N;
    const float4 hv = *(const float4*)&hr[tid << 2];
    const float4 wl = *(const float4*)&w_lam[tid << 2];
    const float4 wo = *(const float4*)&w_out[tid << 2];
    float s_lam = hv.x * wl.x + hv.y * wl.y + hv.z * wl.z + hv.w * wl.w;
    float s_out = hv.x * wo.x + hv.y * wo.y + hv.z * wo.z + hv.w * wo.w;
    #pragma unroll
    for (int off = 32; off > 0; off >>= 1) {
        s_lam += __shfl_down(s_lam, off);
        s_out += __shfl_down(s_out, off);
    }
    __shared__ float redl[4], redo[4];
    const int wid = tid >> 6;
    if ((tid & 63) == 0) { redl[wid] = s_lam; redo[wid] = s_out; }
    __syncthreads();
    if (tid == 0) {
        const float dlam = redl[0] + redl[1] + redl[2] + redl[3];
        const float dout = redo[0] + redo[1] + redo[2] + redo[3];
        const float lam = (n == NSTEPS) ? 1.0f : sigmoidf_(dlam + b_lam[0]);
        const float y_n = dout + b_out[0];
        float un = states[row];
        float ha = states[B_N + row];
        float pm = states[2 * B_N + row];
        float ym = states[3 * B_N + row];
        const float p_n = un * lam;
        un = un * (1.0f - lam);
        const float halt = (u[(size_t)(n - 1) * B_N + row] < lam ? 1.0f : 0.0f) * (1.0f - ha);
        pm = pm * (1.0f - halt) + p_n * halt;
        ym = ym * (1.0f - halt) + y_n * halt;
        ha += halt;
        states[row] = un;
        states[B_N + row] = ha;
        states[2 * B_N + row] = pm;
        states[3 * B_N + row] = ym;
        out_p[(size_t)(n - 1) * B_N + row] = p_n;
        out_y[(size_t)(n - 1) * B_N + row] = y_n;
        if (n == NSTEPS) { out_pm[row] = pm; out_ym[row] = ym; }
    }
}

extern "C" void kernel_launch(void* const* d_in, const int* in_sizes, int n_in,
                              void* d_out, int out_size, void* d_ws, size_t ws_size,
                              hipStream_t stream) {
    const float* x     = (const float*)d_in[0];
    const float* W_ih  = (const float*)d_in[1];
    const float* W_hh  = (const float*)d_in[2];
    const float* b_ih  = (const float*)d_in[3];
    const float* b_hh  = (const float*)d_in[4];
    const float* w_out = (const float*)d_in[5];
    const float* b_out = (const float*)d_in[6];
    const float* w_lam = (const float*)d_in[7];
    const float* b_lam = (const float*)d_in[8];
    const float* u     = (const float*)d_in[9];

    float* out_p  = (float*)d_out;
    float* out_y  = out_p + (size_t)NSTEPS * B_N;
    float* out_pm = out_y + (size_t)NSTEPS * B_N;
    float* out_ym = out_pm + B_N;

    float* ws     = (float*)d_ws;
    float* gx     = ws;                       // B*3H
    float* hA     = gx + (size_t)B_N * G3;    // B*H
    float* hB     = hA + (size_t)B_N * H_N;   // B*H
    float* states = hB + (size_t)B_N * H_N;   // 4*B

    const dim3 blk(256);
    gemm_gx_kernel<<<dim3(G3 / 64, B_N / 64), blk, 0, stream>>>(x, W_ih, b_ih, gx);
    init_h0_kernel<<<dim3(B_N * H_N / 256), blk, 0, stream>>>(gx, b_hh, hA, states);

    float* hc = hA;
    float* hn = hB;
    for (int n = 1; n <= NSTEPS; ++n) {
        halt_kernel<<<dim3(B_N), blk, 0, stream>>>(n, hc, w_out, b_out, w_lam, b_lam, u,
                                                   states, out_p, out_y, out_pm, out_ym);
        if (n < NSTEPS) {
            gemm_step_mfma<<<dim3(H_N / 64, B_N / 128), blk, 0, stream>>>(hc, W_hh, b_hh, gx, hn);
            float* t = hc; hc = hn; hn = t;
        }
    }
}

// Round 3
// 1282.037 us; speedup vs baseline: 2.7479x; 1.5270x over previous
//
#include <hip/hip_runtime.h>
#include <math.h>

// ParityPonderGRU — MFMA split-fp16, pre-split operands + global_load_lds staging.
// B=2048, E=512, H=1024, 20 ponder steps.
// ws layout: gx f32[B*3H] | Whi f16[3H*H] | Wlo f16[3H*H] |
//            hAhi f16[B*H] | hAlo | hBhi | hBlo | states f32[4*B]   (~54.6 MB)

#define B_N 2048
#define E_N 512
#define H_N 1024
#define G3  3072
#define NSTEPS 20
#define BK 32
#define NT (H_N / BK)   // 32 K-steps

typedef __attribute__((ext_vector_type(8))) _Float16 f16x8;
typedef __attribute__((ext_vector_type(4))) _Float16 f16x4v;
typedef __attribute__((ext_vector_type(4))) float    f32x4;

#define GLDS(src, dst) \
  __builtin_amdgcn_global_load_lds( \
      (const __attribute__((address_space(1))) void*)(src), \
      (__attribute__((address_space(3))) void*)(dst), 16, 0, 0)

__device__ __forceinline__ float sigmoidf_(float x) { return 1.0f / (1.0f + expf(-x)); }

// ---------------- Fused step GEMM: gh = h @ W_hh^T (3-product split-fp16 MFMA)
// Block 128(B) x 64(H) x 3 gates; 4 waves 2x2; wave tile 64x32 per gate.
// LDS per buffer (halves): Ahi[0,4096) Alo[4096,8192) Bhi[8192,14336) Blo[14336,20480)
// = 40 KB/buffer, double-buffered = 80 KB. Unpadded [row][32] f16 rows (64 B),
// chunk c = 1 KB = 16 rows x 4 segs, lane-linear (global_load_lds dest order).
__global__ __launch_bounds__(256, 1)
void gemm_step_mfma(const _Float16* __restrict__ h_hi_in,  // [B,H]
                    const _Float16* __restrict__ h_lo_in,  // [B,H]
                    const _Float16* __restrict__ Whi,      // [3H,H]
                    const _Float16* __restrict__ Wlo,      // [3H,H]
                    const float* __restrict__ b_hh,        // [3H]
                    const float* __restrict__ gx,          // [B,3H]
                    _Float16* __restrict__ h_hi_out,
                    _Float16* __restrict__ h_lo_out)
{
  __shared__ _Float16 lds[2][20480];   // 81920 B

  const int tid  = threadIdx.x;
  const int lane = tid & 63;
  const int wv   = tid >> 6;
  const int wr   = wv >> 1;    // row half (0..1)
  const int wc   = wv & 1;     // col half (0..1)
  const int row0 = blockIdx.y * 128;   // over B
  const int col0 = blockIdx.x * 64;    // over H

  // --- per-wave staging chunks: 40 chunks of 1 KB; wave wv owns [wv*10, wv*10+10)
  const _Float16* srcp[10];
  int ldsoff[10];
  #pragma unroll
  for (int j = 0; j < 10; ++j) {
    const int c   = wv * 10 + j;
    const int seg = (lane & 3) * 8;        // k offset in elements
    const _Float16* s;
    if (c < 8) {                                  // A-hi rows 0..127
      const int row = c * 16 + (lane >> 2);
      s = h_hi_in + (size_t)(row0 + row) * H_N + seg;
    } else if (c < 16) {                          // A-lo
      const int row = (c - 8) * 16 + (lane >> 2);
      s = h_lo_in + (size_t)(row0 + row) * H_N + seg;
    } else if (c < 28) {                          // B-hi rows 0..191 (3 gates x 64)
      const int br   = (c - 16) * 16 + (lane >> 2);
      const int wrow = (br >> 6) * H_N + col0 + (br & 63);
      s = Whi + (size_t)wrow * H_N + seg;
    } else {                                      // B-lo
      const int br   = (c - 28) * 16 + (lane >> 2);
      const int wrow = (br >> 6) * H_N + col0 + (br & 63);
      s = Wlo + (size_t)wrow * H_N + seg;
    }
    srcp[j]   = s;
    ldsoff[j] = c * 512;                  // halves
  }

  f32x4 acc[3][4][2];
  #pragma unroll
  for (int g = 0; g < 3; ++g)
    #pragma unroll
    for (int mi = 0; mi < 4; ++mi)
      #pragma unroll
      for (int ni = 0; ni < 2; ++ni)
        acc[g][mi][ni] = (f32x4){0.f, 0.f, 0.f, 0.f};

  const int lrow = lane & 15;
  const int lk   = (lane >> 4) * 8;

  // prologue: stage tile 0 into buffer 0
  #pragma unroll
  for (int j = 0; j < 10; ++j) {
    GLDS(srcp[j], &lds[0][ldsoff[j]]);
    srcp[j] += BK;
  }
  __syncthreads();

  for (int t = 0; t < NT; ++t) {
    const int p = t & 1;
    if (t + 1 < NT) {
      #pragma unroll
      for (int j = 0; j < 10; ++j) {
        GLDS(srcp[j], &lds[p ^ 1][ldsoff[j]]);
        srcp[j] += BK;
      }
    }
    // LDS -> fragments
    f16x8 ah[4], al[4];
    #pragma unroll
    for (int mi = 0; mi < 4; ++mi) {
      const int r = wr * 64 + mi * 16 + lrow;
      ah[mi] = *(const f16x8*)&lds[p][r * 32 + lk];
      al[mi] = *(const f16x8*)&lds[p][4096 + r * 32 + lk];
    }
    f16x8 bh[3][2], bl[3][2];
    #pragma unroll
    for (int g = 0; g < 3; ++g)
      #pragma unroll
      for (int ni = 0; ni < 2; ++ni) {
        const int r = g * 64 + wc * 32 + ni * 16 + lrow;
        bh[g][ni] = *(const f16x8*)&lds[p][8192 + r * 32 + lk];
        bl[g][ni] = *(const f16x8*)&lds[p][14336 + r * 32 + lk];
      }
    #pragma unroll
    for (int g = 0; g < 3; ++g)
      #pragma unroll
      for (int mi = 0; mi < 4; ++mi)
        #pragma unroll
        for (int ni = 0; ni < 2; ++ni) {
          f32x4 c = acc[g][mi][ni];
          c = __builtin_amdgcn_mfma_f32_16x16x32_f16(ah[mi], bh[g][ni], c, 0, 0, 0);
          c = __builtin_amdgcn_mfma_f32_16x16x32_f16(ah[mi], bl[g][ni], c, 0, 0, 0);
          c = __builtin_amdgcn_mfma_f32_16x16x32_f16(al[mi], bh[g][ni], c, 0, 0, 0);
          acc[g][mi][ni] = c;
        }
    __syncthreads();
  }

  // Gate epilogue: D frag mapping col=lane&15, row=(lane>>4)*4+r  [m89]
  #pragma unroll
  for (int mi = 0; mi < 4; ++mi) {
    #pragma unroll
    for (int ni = 0; ni < 2; ++ni) {
      const int n = col0 + wc * 32 + ni * 16 + lrow;
      const float bhr = b_hh[n];
      const float bhz = b_hh[H_N + n];
      const float bhn = b_hh[2 * H_N + n];
      #pragma unroll
      for (int r = 0; r < 4; ++r) {
        const int m = row0 + wr * 64 + mi * 16 + (lane >> 4) * 4 + r;
        const float gr = acc[0][mi][ni][r] + bhr;
        const float gz = acc[1][mi][ni][r] + bhz;
        const float gn = acc[2][mi][ni][r] + bhn;
        const size_t gxb = (size_t)m * G3;
        const float rr = sigmoidf_(gx[gxb + n] + gr);
        const float zz = sigmoidf_(gx[gxb + H_N + n] + gz);
        const float nn = tanhf(gx[gxb + 2 * H_N + n] + rr * gn);
        const size_t hidx = (size_t)m * H_N + n;
        const float hold = (float)h_hi_in[hidx] + (float)h_lo_in[hidx];
        const float hf = (1.f - zz) * nn + zz * hold;
        const _Float16 hh = (_Float16)hf;
        h_hi_out[hidx] = hh;
        h_lo_out[hidx] = (_Float16)(hf - (float)hh);
      }
    }
  }
}

// ---------------- one-time: split W_hh into fp16 hi/lo ---------------------
__global__ __launch_bounds__(256)
void split_whh_kernel(const float* __restrict__ W_hh,
                      _Float16* __restrict__ Whi, _Float16* __restrict__ Wlo)
{
  const size_t base = ((size_t)blockIdx.x * 256 + threadIdx.x) * 4;
  const float4 w = *(const float4*)&W_hh[base];
  float s[4] = {w.x, w.y, w.z, w.w};
  f16x4v hi, lo;
  #pragma unroll
  for (int e = 0; e < 4; ++e) {
    const _Float16 h = (_Float16)s[e];
    hi[e] = h;
    lo[e] = (_Float16)(s[e] - (float)h);
  }
  *(f16x4v*)&Whi[base] = hi;
  *(f16x4v*)&Wlo[base] = lo;
}

// ---------------- GEMM: gx = x @ W_ih^T + b_ih  (fp32, one-time) ----------
__global__ __launch_bounds__(256)
void gemm_gx_kernel(const float* __restrict__ x,
                    const float* __restrict__ W_ih,
                    const float* __restrict__ b_ih,
                    float* __restrict__ gx)
{
    __shared__ float As[16][68];
    __shared__ float Bs[16][68];
    const int tid = threadIdx.x;
    const int tx = tid & 15, ty = tid >> 4;
    const int row0 = blockIdx.y * 64;
    const int col0 = blockIdx.x * 64;
    const int lr = tid >> 2;
    const int lk = (tid & 3) << 2;
    float acc[4][4] = {};
    for (int k0 = 0; k0 < E_N; k0 += 16) {
        float4 av = *(const float4*)(x    + (size_t)(row0 + lr) * E_N + k0 + lk);
        float4 bv = *(const float4*)(W_ih + (size_t)(col0 + lr) * E_N + k0 + lk);
        As[lk+0][lr] = av.x; As[lk+1][lr] = av.y; As[lk+2][lr] = av.z; As[lk+3][lr] = av.w;
        Bs[lk+0][lr] = bv.x; Bs[lk+1][lr] = bv.y; Bs[lk+2][lr] = bv.z; Bs[lk+3][lr] = bv.w;
        __syncthreads();
        #pragma unroll
        for (int k = 0; k < 16; ++k) {
            float4 a4 = *(const float4*)&As[k][ty << 2];
            float4 b4 = *(const float4*)&Bs[k][tx << 2];
            float aa[4] = {a4.x, a4.y, a4.z, a4.w};
            float bb[4] = {b4.x, b4.y, b4.z, b4.w};
            #pragma unroll
            for (int i = 0; i < 4; ++i)
                #pragma unroll
                for (int j = 0; j < 4; ++j)
                    acc[i][j] = fmaf(aa[i], bb[j], acc[i][j]);
        }
        __syncthreads();
    }
    #pragma unroll
    for (int i = 0; i < 4; ++i) {
        const int r = row0 + (ty << 2) + i;
        #pragma unroll
        for (int j = 0; j < 4; ++j) {
            const int c = col0 + (tx << 2) + j;
            gx[(size_t)r * G3 + c] = acc[i][j] + b_ih[c];
        }
    }
}

// ---------------- h0 = gru_cell(x, 0): gh = b_hh; init states --------------
__global__ __launch_bounds__(256)
void init_h0_kernel(const float* __restrict__ gx, const float* __restrict__ b_hh,
                    _Float16* __restrict__ h_hi, _Float16* __restrict__ h_lo,
                    float* __restrict__ states)
{
    const int idx = blockIdx.x * 256 + threadIdx.x;
    const int r = idx >> 10;
    const int c = idx & (H_N - 1);
    const float rr = sigmoidf_(gx[(size_t)r * G3 + c] + b_hh[c]);
    const float zz = sigmoidf_(gx[(size_t)r * G3 + H_N + c] + b_hh[H_N + c]);
    const float nn = tanhf(gx[(size_t)r * G3 + 2 * H_N + c] + rr * b_hh[2 * H_N + c]);
    const float hf = (1.0f - zz) * nn;
    const _Float16 hh = (_Float16)hf;
    h_hi[idx] = hh;
    h_lo[idx] = (_Float16)(hf - (float)hh);
    if (idx < B_N) {
        states[idx]           = 1.0f;
        states[B_N + idx]     = 0.0f;
        states[2 * B_N + idx] = 0.0f;
        states[3 * B_N + idx] = 0.0f;
    }
}

// ---------------- Per-step halting -----------------------------------------
__global__ __launch_bounds__(256)
void halt_kernel(const int n,
                 const _Float16* __restrict__ h_hi, const _Float16* __restrict__ h_lo,
                 const float* __restrict__ w_out, const float* __restrict__ b_out,
                 const float* __restrict__ w_lam, const float* __restrict__ b_lam,
                 const float* __restrict__ u,
                 float* __restrict__ states,
                 float* __restrict__ out_p, float* __restrict__ out_y,
                 float* __restrict__ out_pm, float* __restrict__ out_ym)
{
    const int row = blockIdx.x;
    const int tid = threadIdx.x;
    const size_t base = (size_t)row * H_N + (tid << 2);
    const f16x4v hh4 = *(const f16x4v*)&h_hi[base];
    const f16x4v hl4 = *(const f16x4v*)&h_lo[base];
    const float4 wl = *(const float4*)&w_lam[tid << 2];
    const float4 wo = *(const float4*)&w_out[tid << 2];
    float hv[4];
    #pragma unroll
    for (int e = 0; e < 4; ++e) hv[e] = (float)hh4[e] + (float)hl4[e];
    float s_lam = hv[0] * wl.x + hv[1] * wl.y + hv[2] * wl.z + hv[3] * wl.w;
    float s_out = hv[0] * wo.x + hv[1] * wo.y + hv[2] * wo.z + hv[3] * wo.w;
    #pragma unroll
    for (int off = 32; off > 0; off >>= 1) {
        s_lam += __shfl_down(s_lam, off);
        s_out += __shfl_down(s_out, off);
    }
    __shared__ float redl[4], redo[4];
    const int wid = tid >> 6;
    if ((tid & 63) == 0) { redl[wid] = s_lam; redo[wid] = s_out; }
    __syncthreads();
    if (tid == 0) {
        const float dlam = redl[0] + redl[1] + redl[2] + redl[3];
        const float dout = redo[0] + redo[1] + redo[2] + redo[3];
        const float lam = (n == NSTEPS) ? 1.0f : sigmoidf_(dlam + b_lam[0]);
        const float y_n = dout + b_out[0];
        float un = states[row];
        float ha = states[B_N + row];
        float pm = states[2 * B_N + row];
        float ym = states[3 * B_N + row];
        const float p_n = un * lam;
        un = un * (1.0f - lam);
        const float halt = (u[(size_t)(n - 1) * B_N + row] < lam ? 1.0f : 0.0f) * (1.0f - ha);
        pm = pm * (1.0f - halt) + p_n * halt;
        ym = ym * (1.0f - halt) + y_n * halt;
        ha += halt;
        states[row] = un;
        states[B_N + row] = ha;
        states[2 * B_N + row] = pm;
        states[3 * B_N + row] = ym;
        out_p[(size_t)(n - 1) * B_N + row] = p_n;
        out_y[(size_t)(n - 1) * B_N + row] = y_n;
        if (n == NSTEPS) { out_pm[row] = pm; out_ym[row] = ym; }
    }
}

extern "C" void kernel_launch(void* const* d_in, const int* in_sizes, int n_in,
                              void* d_out, int out_size, void* d_ws, size_t ws_size,
                              hipStream_t stream) {
    const float* x     = (const float*)d_in[0];
    const float* W_ih  = (const float*)d_in[1];
    const float* W_hh  = (const float*)d_in[2];
    const float* b_ih  = (const float*)d_in[3];
    const float* b_hh  = (const float*)d_in[4];
    const float* w_out = (const float*)d_in[5];
    const float* b_out = (const float*)d_in[6];
    const float* w_lam = (const float*)d_in[7];
    const float* b_lam = (const float*)d_in[8];
    const float* u     = (const float*)d_in[9];

    float* out_p  = (float*)d_out;
    float* out_y  = out_p + (size_t)NSTEPS * B_N;
    float* out_pm = out_y + (size_t)NSTEPS * B_N;
    float* out_ym = out_pm + B_N;

    float* ws = (float*)d_ws;
    float*     gx   = ws;                                    // B*3H f32
    _Float16*  Whi  = (_Float16*)(gx + (size_t)B_N * G3);    // 3H*H f16
    _Float16*  Wlo  = Whi + (size_t)G3 * H_N;
    _Float16*  hAhi = Wlo + (size_t)G3 * H_N;                // B*H f16
    _Float16*  hAlo = hAhi + (size_t)B_N * H_N;
    _Float16*  hBhi = hAlo + (size_t)B_N * H_N;
    _Float16*  hBlo = hBhi + (size_t)B_N * H_N;
    float*     states = (float*)(hBlo + (size_t)B_N * H_N);  // 4*B f32

    const dim3 blk(256);
    split_whh_kernel<<<dim3((size_t)G3 * H_N / 1024), blk, 0, stream>>>(W_hh, Whi, Wlo);
    gemm_gx_kernel<<<dim3(G3 / 64, B_N / 64), blk, 0, stream>>>(x, W_ih, b_ih, gx);
    init_h0_kernel<<<dim3(B_N * H_N / 256), blk, 0, stream>>>(gx, b_hh, hAhi, hAlo, states);

    _Float16 *hchi = hAhi, *hclo = hAlo, *hnhi = hBhi, *hnlo = hBlo;
    for (int n = 1; n <= NSTEPS; ++n) {
        halt_kernel<<<dim3(B_N), blk, 0, stream>>>(n, hchi, hclo, w_out, b_out, w_lam, b_lam, u,
                                                   states, out_p, out_y, out_pm, out_ym);
        if (n < NSTEPS) {
            gemm_step_mfma<<<dim3(H_N / 64, B_N / 128), blk, 0, stream>>>(
                hchi, hclo, Whi, Wlo, b_hh, gx, hnhi, hnlo);
            _Float16* t;
            t = hchi; hchi = hnhi; hnhi = t;
            t = hclo; hclo = hnlo; hnlo = t;
        }
    }
}